// Round 1
// baseline (208.344 us; speedup 1.0000x reference)
//
#include <hip/hip_runtime.h>

// Problem constants (from reference): S=16, P=65536, N=256, K=32
#define S_DIM 16
#define P_DIM 65536
#define N_ROWS 256
#define K_IDX 32
#define NP ((size_t)N_ROWS * P_DIM)   // 16,777,216 elements per channel

// ---------------------------------------------------------------------------
// Fused fill+scatter: ONE pass writes every output element exactly once.
// No memset (the old path memset 805 MB -- 4x the 201 MB output -- because
// out_size is in BYTES; either way a second full-buffer pass is pure waste).
//
// Decomposition: 2048 blocks x 256 threads. block = (row n, 1/8th of P).
// Each thread writes ITEMS=8 float4 per channel; lanes are consecutive
// float4 -> fully coalesced stores. Per float4 (4 p's), a 32-wide unsigned
// range test detects whether ANY of the row's 32 indices lands in [p0,p0+4);
// ~96 VALU ops per 48 B stored, far under the HBM write roofline, so the
// compare loop hides under the store stream. Hit path (rare: 32/65536 p's
// per row) computes exact multiplicities and 1-(1-v)^cnt by repeated
// multiply (exact for integer exponents; matched absmax 0.0 previously).
// ---------------------------------------------------------------------------
#define CHUNKS_PER_ROW 8
#define ITEMS 8   // 256 thr * 8 items * 4 floats = 8192 p per chunk

__global__ __launch_bounds__(256) void fused_build(
    const float* __restrict__ schema_params, // (S,P,4)
    const int*   __restrict__ schema_ids,    // (N)
    const int*   __restrict__ indices,       // (N,K)
    float*       __restrict__ out)           // (3,N,P)
{
    const int tid   = threadIdx.x;
    const int n     = blockIdx.x >> 3;                    // row 0..255
    const int chunk = blockIdx.x & (CHUNKS_PER_ROW - 1);  // 0..7

    __shared__ int sh_idx[K_IDX];
    __shared__ int sh_s;
    if (tid < K_IDX) sh_idx[tid] = indices[n * K_IDX + tid];
    if (tid == 0)    sh_s = schema_ids[n];
    __syncthreads();

    // Keep the row's 32 indices in registers: the compare loop runs 8 times
    // per thread; LDS re-reads (32 ds_read/item) would throttle the stream.
    int idx[K_IDX];
#pragma unroll
    for (int j = 0; j < K_IDX; ++j) idx[j] = sh_idx[j];
    const int s = sh_s;

    float* __restrict__ o0 = out + (size_t)n * P_DIM;
    float* __restrict__ o1 = o0 + NP;
    float* __restrict__ o2 = o0 + 2 * NP;

    const int base_p = chunk * (P_DIM / CHUNKS_PER_ROW);  // chunk * 8192

    for (int it = 0; it < ITEMS; ++it) {
        const int p0 = base_p + (it * 256 + tid) * 4;

        // Fast reject: does any index fall in [p0, p0+4)?
        unsigned hit = 0u;
#pragma unroll
        for (int j = 0; j < K_IDX; ++j)
            hit |= (unsigned)((unsigned)(idx[j] - p0) < 4u);

        float4 r0 = make_float4(0.f, 0.f, 0.f, 0.f);
        float4 r1 = r0, r2 = r0;

        if (hit) {  // rare: ~32 of 16384 float4-groups per row
            int c0 = 0, c1 = 0, c2 = 0, c3 = 0;
#pragma unroll
            for (int j = 0; j < K_IDX; ++j) {
                const unsigned u = (unsigned)(idx[j] - p0);
                c0 += (u == 0u); c1 += (u == 1u);
                c2 += (u == 2u); c3 += (u == 3u);
            }
            const int cc[4] = {c0, c1, c2, c3};
            float t0[4], t1[4], t2[4];
#pragma unroll
            for (int m = 0; m < 4; ++m) {
                float a0 = 0.f, a1 = 0.f, a2 = 0.f;
                if (cc[m] > 0) {
                    // PROJ rows: c0 = f2+f3, c1 = f1, c2 = f3
                    const float4 f = *reinterpret_cast<const float4*>(
                        schema_params + ((size_t)s * P_DIM + (size_t)(p0 + m)) * 4);
                    const float b0 = 1.0f - (f.z + f.w);
                    const float b1 = 1.0f - f.y;
                    const float b2 = 1.0f - f.w;
                    float q0 = 1.f, q1 = 1.f, q2 = 1.f;
                    for (int i = 0; i < cc[m]; ++i) { q0 *= b0; q1 *= b1; q2 *= b2; }
                    a0 = 1.0f - q0; a1 = 1.0f - q1; a2 = 1.0f - q2;
                }
                t0[m] = a0; t1[m] = a1; t2[m] = a2;
            }
            r0 = make_float4(t0[0], t0[1], t0[2], t0[3]);
            r1 = make_float4(t1[0], t1[1], t1[2], t1[3]);
            r2 = make_float4(t2[0], t2[1], t2[2], t2[3]);
        }

        *reinterpret_cast<float4*>(o0 + p0) = r0;
        *reinterpret_cast<float4*>(o1 + p0) = r1;
        *reinterpret_cast<float4*>(o2 + p0) = r2;
    }
}

extern "C" void kernel_launch(void* const* d_in, const int* in_sizes, int n_in,
                              void* d_out, int out_size, void* d_ws, size_t ws_size,
                              hipStream_t stream) {
    const float* schema_params = (const float*)d_in[0]; // (16, 65536, 4) f32
    const int*   schema_ids    = (const int*)d_in[1];   // (256,) i32
    const int*   indices       = (const int*)d_in[2];   // (256, 32) i32
    float*       out           = (float*)d_out;         // (3, 256, 65536) f32

    // Single full-coverage pass: 2048 blocks (8 blocks/CU -> 32 waves/CU),
    // writes exactly 3*N*P*4 = 201.3 MB. No memset dispatch at all.
    fused_build<<<N_ROWS * CHUNKS_PER_ROW, 256, 0, stream>>>(
        schema_params, schema_ids, indices, out);
}

// Round 2
// 200.959 us; speedup vs baseline: 1.0367x; 1.0367x over previous
//
#include <hip/hip_runtime.h>

// Problem constants (from reference): S=16, P=65536, N=256, K=32
#define S_DIM 16
#define P_DIM 65536
#define N_ROWS 256
#define K_IDX 32
#define NP ((size_t)N_ROWS * P_DIM)   // 16,777,216 elements per channel

// Logical output: 3 channels x N x P floats = 201,326,592 bytes.
// Computed from problem constants -- deliberately NOT from out_size, whose
// unit is ambiguous (round-0/1 profiles show 805 MB = out_size*4 fills, i.e.
// out_size is already in bytes; filling out_size*4 wastes ~90 us per run).
#define OUT_BYTES (3ull * NP * 4ull)

// ---------------------------------------------------------------------------
// Scatter the nonzero values (output zeroed by the vendor fill first; the
// fill path measured 6.55-6.8 TB/s on this device and is graph-capturable).
// Thread t of block b handles (n = b*8 + t/32, k = t%32).
// count[n,p] = multiplicity of p within indices[n,:] (LDS row broadcast,
// 32 comparisons). out[c,n,p] = 1 - (1 - v_c)^count by repeated multiply
// (exact for integer exponents; count is almost always 1).
// Duplicate k within a row write the same value to the same address: benign.
// This exact structure measured absmax 0.0 in round 0.
// ---------------------------------------------------------------------------
__global__ void scatter_kernel(const float* __restrict__ schema_params, // (S,P,4)
                               const int* __restrict__ schema_ids,      // (N)
                               const int* __restrict__ indices,         // (N,K)
                               float* __restrict__ out) {               // (3,N,P)
    __shared__ int lidx[8][K_IDX];

    const int t = threadIdx.x;          // 0..255
    const int nlocal = t >> 5;          // 0..7
    const int k = t & 31;               // 0..31
    const int n = blockIdx.x * 8 + nlocal;

    // Coalesced: global index = blockIdx.x*256 + t
    const int p = indices[n * K_IDX + k];
    lidx[nlocal][k] = p;
    __syncthreads();

    int cnt = 0;
#pragma unroll
    for (int j = 0; j < K_IDX; ++j) {
        cnt += (lidx[nlocal][j] == p) ? 1 : 0;
    }

    const int s = schema_ids[n];
    // (s*P + p)*4 floats -> 16B aligned float4
    const float4 f = *reinterpret_cast<const float4*>(
        schema_params + ((size_t)s * P_DIM + (size_t)p) * 4);

    // PROJ rows: c0 = f2 + f3, c1 = f1, c2 = f3
    const float v0 = f.z + f.w;
    const float v1 = f.y;
    const float v2 = f.w;

    const float b0 = 1.0f - v0;
    const float b1 = 1.0f - v1;
    const float b2 = 1.0f - v2;

    float r0 = 1.0f, r1 = 1.0f, r2 = 1.0f;
    for (int i = 0; i < cnt; ++i) {  // cnt >= 1 always (p matches itself)
        r0 *= b0;
        r1 *= b1;
        r2 *= b2;
    }

    const size_t off = (size_t)n * P_DIM + (size_t)p;
    out[off]          = 1.0f - r0;
    out[NP + off]     = 1.0f - r1;
    out[2 * NP + off] = 1.0f - r2;
}

extern "C" void kernel_launch(void* const* d_in, const int* in_sizes, int n_in,
                              void* d_out, int out_size, void* d_ws, size_t ws_size,
                              hipStream_t stream) {
    const float* schema_params = (const float*)d_in[0]; // (16, 65536, 4) f32
    const int*   schema_ids    = (const int*)d_in[1];   // (256,) i32
    const int*   indices       = (const int*)d_in[2];   // (256, 32) i32
    float*       out           = (float*)d_out;         // (3, 256, 65536) f32 concat

    // 1) zero-fill EXACTLY the logical output (201.3 MB, ~30 us at the
    //    vendor fill's 6.6 TB/s) -- round 0 filled out_size*4 = 805 MB
    //    (~121 us), 4x the logical output, because out_size is in bytes.
    (void)hipMemsetAsync(d_out, 0, OUT_BYTES, stream);

    // 2) scatter: 256 rows * 32 idx = 8192 threads = 32 blocks of 256
    scatter_kernel<<<N_ROWS * K_IDX / 256, 256, 0, stream>>>(
        schema_params, schema_ids, indices, out);
}